// Round 16
// baseline (390.807 us; speedup 1.0000x reference)
//
#include <hip/hip_runtime.h>

#define NN 100000
#define NNP 100096            // padded row count (multiple of 256)
#define NE 1600000
#define NBK 391               // node buckets of 256 (dst >> 8)
#define CAP 4608              // fixed bucket capacity (mean 4096, +8 sigma)
#define SCCH 4096             // edges per scatter block
#define NSC ((NE + SCCH - 1) / SCCH)   // 391
#define MMG 782               // layer-0 mm grid (NNP/256 * 2)
#define FAGGB 1563            // fused agg+mm grid: ceil(NN/64)

typedef __attribute__((ext_vector_type(8))) short bf16x8;
typedef __attribute__((ext_vector_type(4))) float f32x4;

__device__ __forceinline__ float bf2f(unsigned short u) {
    unsigned int v = ((unsigned int)u) << 16;
    return __builtin_bit_cast(float, v);
}
__device__ __forceinline__ unsigned short f2bf(float f) {
    unsigned int u = __builtin_bit_cast(unsigned int, f);
    u += 0x7FFFu + ((u >> 16) & 1u);          // RNE
    return (unsigned short)(u >> 16);
}
__device__ __forceinline__ unsigned int pk2(float lo, float hi) {
    return (unsigned int)f2bf(lo) | ((unsigned int)f2bf(hi) << 16);
}
__device__ __forceinline__ float bflo(unsigned int v) {
    return __builtin_bit_cast(float, v << 16);
}
__device__ __forceinline__ float bfhi(unsigned int v) {
    return __builtin_bit_cast(float, v & 0xFFFF0000u);
}

// bijective XCD-pair map (round-robin dispatch assumed): halves (g, g^1) of a
// row-block land on the same XCD so the second half's A reads hit L2.
__device__ __forceinline__ int mm_gmap(int bid, int off) {
    int x = (bid + off) & 7;
    int j = bid >> 3;
    int g = j;
#pragma unroll
    for (int u = 0; u < 8; ++u)
        if (u < x) g += ((((u - off) & 7) < 6) ? 98 : 97);
    return g;
}

// ---------------- prep: W -> WT bf16, bcur init ----------------

__global__ __launch_bounds__(256) void k_prep(const float* __restrict__ Wl_stack,
                                              const float* __restrict__ Wr_stack,
                                              const float* __restrict__ Wl_out,
                                              const float* __restrict__ Wr_out,
                                              unsigned short* __restrict__ WT,
                                              int* __restrict__ bcur) {
    int i = blockIdx.x * 256 + threadIdx.x;
    const int L3OFF = 3 * 256 * 128;     // 98304
    const int TOT = L3OFF + 128 * 128;   // 114688
    if (i < TOT) {
        float v;
        if (i < L3OFF) {
            int l = i / (256 * 128);
            int r = i % (256 * 128);
            int c = r / 128;
            int k = r % 128;
            v = (c < 128) ? Wl_stack[(size_t)(l * 128 + k) * 128 + c]
                          : Wr_stack[(size_t)(l * 128 + k) * 128 + (c - 128)];
        } else {
            int r = i - L3OFF;
            int c = r / 128;
            int k = r % 128;
            v = (c < 64) ? Wl_out[(size_t)k * 64 + c]
                         : Wr_out[(size_t)k * 64 + (c - 64)];
        }
        WT[i] = f2bf(v);
    } else if (i - TOT < NBK) {
        bcur[i - TOT] = (i - TOT) * CAP;
    }
}

// ---------------- device bodies ----------------

__device__ __forceinline__ void scatter_body(int bid, int tid,
                                             const int* __restrict__ src,
                                             const int* __restrict__ dst,
                                             int* __restrict__ bcur,
                                             unsigned int* __restrict__ ebuf,
                                             unsigned char* smem) {
    int* lh = (int*)smem;
    int* lbase = lh + NBK;
    for (int i = tid; i < NBK; i += 256) lh[i] = 0;
    __syncthreads();
    int base = bid * SCCH;
    int lim = min(SCCH, NE - base);
    for (int i = tid; i < lim; i += 256)
        atomicAdd(&lh[dst[base + i] >> 8], 1);
    __syncthreads();
    for (int i = tid; i < NBK; i += 256)
        lbase[i] = lh[i] ? atomicAdd(&bcur[i], lh[i]) : 0;
    __syncthreads();
    for (int i = tid; i < NBK; i += 256) lh[i] = 0;
    __syncthreads();
    for (int i = tid; i < lim; i += 256) {
        int d = dst[base + i];
        int s = src[base + i];
        int b = d >> 8;
        int off = atomicAdd(&lh[b], 1);
        ebuf[(size_t)lbase[b] + off] = ((unsigned)s << 8) | (unsigned)(d & 255);
    }
}

// layer-0 GEMM body (fp32 x input). Block = 256 rows x 128 cols (one half).
// WT half staged in LDS with XOR swizzle; operand-swapped MFMA; uint2 stores.
__device__ __forceinline__ void mm0_body(int bid, int xoff, int tid,
                                         const float* __restrict__ Ain,
                                         const unsigned short* __restrict__ WT,
                                         unsigned short* __restrict__ Y,
                                         unsigned short* __restrict__ Z,
                                         unsigned char* lds) {
    int wave = tid >> 6, l = tid & 63;
    int lrow = l & 15, g = l >> 4;
    int gm = mm_gmap(bid, xoff);
    int half = gm & 1;
    int rowblk = gm >> 1;
    int rbase = rowblk * 256 + wave * 64;

    {
        const unsigned char* wsrc = (const unsigned char*)(WT + (size_t)half * 128 * 128);
#pragma unroll
        for (int j = 0; j < 8; ++j) {
            int lin = (j * 256 + tid) * 16;
            uint4 v = *(const uint4*)(wsrc + lin);
            int row = lin >> 8;
            int colb = lin & 255;
            *(uint4*)(lds + row * 256 + (colb ^ ((row & 7) << 4))) = v;
        }
    }

    bf16x8 af[4][4];
#pragma unroll
    for (int s = 0; s < 4; ++s) {
        int row = rbase + s * 16 + lrow;
        int rc = row < NN ? row : NN - 1;   // x not padded past NN
#pragma unroll
        for (int ks = 0; ks < 4; ++ks) {
            const float* ap = Ain + (size_t)rc * 128 + ks * 32 + g * 8;
            float4 a = *(const float4*)ap;
            float4 b = *(const float4*)(ap + 4);
            uint4 u;
            u.x = pk2(a.x, a.y); u.y = pk2(a.z, a.w);
            u.z = pk2(b.x, b.y); u.w = pk2(b.z, b.w);
            af[s][ks] = __builtin_bit_cast(bf16x8, u);
        }
    }
    __syncthreads();

#pragma unroll
    for (int cg = 0; cg < 8; ++cg) {
        int c0 = cg * 16;
        int rl = c0 + lrow;
        bf16x8 bfr[4];
#pragma unroll
        for (int ks = 0; ks < 4; ++ks) {
            int colb = ks * 64 + g * 16;
            bfr[ks] = *(const bf16x8*)(lds + rl * 256 + (colb ^ ((rl & 7) << 4)));
        }
        int gc0 = half * 128 + c0;
        unsigned short* dstp = (gc0 < 128) ? Y : Z;
        int cb = ((gc0 < 128) ? gc0 : gc0 - 128) + g * 4;
#pragma unroll
        for (int s = 0; s < 4; ++s) {
            f32x4 acc = {0.f, 0.f, 0.f, 0.f};
#pragma unroll
            for (int ks = 0; ks < 4; ++ks)
                acc = __builtin_amdgcn_mfma_f32_16x16x32_bf16(bfr[ks], af[s][ks], acc, 0, 0, 0);
            int row = rbase + s * 16 + lrow;
            uint2 w;
            w.x = pk2(acc[0], acc[1]);
            w.y = pk2(acc[2], acc[3]);
            *(uint2*)(dstp + (size_t)row * 128 + cb) = w;
        }
    }
}

// ---------------- fused dispatch: scatter (indep) + layer-0 GEMM ----------------

__global__ __launch_bounds__(256) void k_fused0(const int* __restrict__ src,
                                                const int* __restrict__ dst,
                                                int* __restrict__ bcur,
                                                unsigned int* __restrict__ ebuf,
                                                const float* __restrict__ x,
                                                const unsigned short* __restrict__ WT,
                                                unsigned short* __restrict__ Y,
                                                unsigned short* __restrict__ Z) {
    __shared__ unsigned char smem[32768];
    int tid = threadIdx.x;
    if (blockIdx.x < NSC) {
        scatter_body(blockIdx.x, tid, src, dst, bcur, ebuf, smem);
    } else {
        mm0_body(blockIdx.x - NSC, 7, tid, x, WT, Y, Z, smem);   // xoff: NSC%8=7
    }
}

// ---------------- per-bucket CSR finalize ----------------

__global__ __launch_bounds__(256) void kb_csr(const unsigned int* __restrict__ ebuf,
                                              const int* __restrict__ bcur,
                                              int* __restrict__ row_beg,
                                              int* __restrict__ row_end,
                                              int* __restrict__ csr) {
    __shared__ int sdeg[256], spre[256];
    int bkt = blockIdx.x;
    int tid = threadIdx.x;
    int nbase = bkt << 8;
    int ebeg = bkt * CAP;
    int eend = bcur[bkt];
    sdeg[tid] = 0;
    __syncthreads();
    for (int e = ebeg + tid; e < eend; e += 256)
        atomicAdd(&sdeg[ebuf[e] & 255], 1);
    __syncthreads();
    spre[tid] = sdeg[tid];
    __syncthreads();
#pragma unroll
    for (int off = 1; off < 256; off <<= 1) {
        int t = (tid >= off) ? spre[tid - off] : 0;
        __syncthreads();
        if (tid >= off) spre[tid] += t;
        __syncthreads();
    }
    int excl = spre[tid] - sdeg[tid];
    if (nbase + tid < NN) {
        row_beg[nbase + tid] = ebeg + excl;
        row_end[nbase + tid] = ebeg + excl + sdeg[tid];
    }
    __syncthreads();
    sdeg[tid] = excl;
    __syncthreads();
    for (int e = ebeg + tid; e < eend; e += 256) {
        unsigned int v = ebuf[e];
        int p = atomicAdd(&sdeg[v & 255], 1);
        csr[ebeg + p] = (int)(v >> 8);
    }
}

// ---------------- fused aggregation + next-layer GEMM ----------------
// Block = 64 nodes, 4 waves. Phase 1: wave w aggregates nodes w*16..w*16+15
// (identical gather as k_aggb), LeakyReLU, h-row -> swizzled LDS tile [64][256B].
// Phase 2: dual GEMM h(64x128) @ WTn(128 x N2) -> Yn|Zn, wave w covers N2/4 cols.

template <int NOUTN>
__global__ __launch_bounds__(256) void k_fagg(const unsigned short* __restrict__ Y,
                                              const unsigned short* __restrict__ Z,
                                              const int* __restrict__ row_beg,
                                              const int* __restrict__ row_end,
                                              const int* __restrict__ csr,
                                              const float* __restrict__ b,
                                              const unsigned short* __restrict__ WTn,
                                              unsigned short* __restrict__ Yn,
                                              unsigned short* __restrict__ Zn) {
    constexpr int N2 = 2 * NOUTN;               // 256 or 128
    constexpr int CGB = N2 / 64;                // col 16-blocks per wave: 4 or 2
    __shared__ unsigned char hlds[64 * 256];    // 16 KB

    int tid = threadIdx.x;
    int wave = tid >> 6, lane = tid & 63;
    int lrow = lane & 15, g = lane >> 4;
    int nodebase = blockIdx.x * 64;
    const int lane2 = lane * 2;

    // ---- phase 1: aggregation (16 nodes per wave) ----
    for (int r = 0; r < 16; ++r) {
        int rl = wave * 16 + r;
        int n = __builtin_amdgcn_readfirstlane(nodebase + rl);
        float o0 = 0.f, o1 = 0.f;
        if (n < NN) {
            int beg = __builtin_amdgcn_readfirstlane(row_beg[n]);
            int end = __builtin_amdgcn_readfirstlane(row_end[n]);
            float inv = (end > beg) ? 1.0f / (float)(end - beg) : 0.0f;
            float a0 = 0.f, a1 = 0.f;
            int e = beg;
            for (; e + 8 <= end; e += 8) {
                int s0 = csr[e + 0], s1 = csr[e + 1], s2 = csr[e + 2], s3 = csr[e + 3];
                int s4 = csr[e + 4], s5 = csr[e + 5], s6 = csr[e + 6], s7 = csr[e + 7];
                unsigned int v0 = *(const unsigned int*)(Y + (size_t)s0 * 128 + lane2);
                unsigned int v1 = *(const unsigned int*)(Y + (size_t)s1 * 128 + lane2);
                unsigned int v2 = *(const unsigned int*)(Y + (size_t)s2 * 128 + lane2);
                unsigned int v3 = *(const unsigned int*)(Y + (size_t)s3 * 128 + lane2);
                unsigned int v4 = *(const unsigned int*)(Y + (size_t)s4 * 128 + lane2);
                unsigned int v5 = *(const unsigned int*)(Y + (size_t)s5 * 128 + lane2);
                unsigned int v6 = *(const unsigned int*)(Y + (size_t)s6 * 128 + lane2);
                unsigned int v7 = *(const unsigned int*)(Y + (size_t)s7 * 128 + lane2);
                a0 += bflo(v0) + bflo(v1) + bflo(v2) + bflo(v3)
                    + bflo(v4) + bflo(v5) + bflo(v6) + bflo(v7);
                a1 += bfhi(v0) + bfhi(v1) + bfhi(v2) + bfhi(v3)
                    + bfhi(v4) + bfhi(v5) + bfhi(v6) + bfhi(v7);
            }
            for (; e + 4 <= end; e += 4) {
                int s0 = csr[e + 0], s1 = csr[e + 1], s2 = csr[e + 2], s3 = csr[e + 3];
                unsigned int v0 = *(const unsigned int*)(Y + (size_t)s0 * 128 + lane2);
                unsigned int v1 = *(const unsigned int*)(Y + (size_t)s1 * 128 + lane2);
                unsigned int v2 = *(const unsigned int*)(Y + (size_t)s2 * 128 + lane2);
                unsigned int v3 = *(const unsigned int*)(Y + (size_t)s3 * 128 + lane2);
                a0 += bflo(v0) + bflo(v1) + bflo(v2) + bflo(v3);
                a1 += bfhi(v0) + bfhi(v1) + bfhi(v2) + bfhi(v3);
            }
            for (; e < end; ++e) {
                int s = csr[e];
                unsigned int v = *(const unsigned int*)(Y + (size_t)s * 128 + lane2);
                a0 += bflo(v);
                a1 += bfhi(v);
            }
            unsigned int zv = *(const unsigned int*)(Z + (size_t)n * 128 + lane2);
            float2 bb = *(const float2*)(b + lane2);
            o0 = a0 * inv + bflo(zv) + bb.x;
            o1 = a1 * inv + bfhi(zv) + bb.y;
            o0 = o0 > 0.f ? o0 : 0.1f * o0;     // LeakyReLU (all fused layers)
            o1 = o1 > 0.f ? o1 : 0.1f * o1;
        }
        *(unsigned int*)(hlds + rl * 256 + ((lane * 4) ^ ((rl & 7) << 4))) = pk2(o0, o1);
    }
    __syncthreads();

    // ---- phase 2: dual GEMM from LDS h-tile ----
    bf16x8 af[4][4];
#pragma unroll
    for (int s = 0; s < 4; ++s) {
        int row = s * 16 + lrow;
#pragma unroll
        for (int ks = 0; ks < 4; ++ks) {
            int colb = ks * 64 + g * 16;
            af[s][ks] = *(const bf16x8*)(hlds + row * 256 + (colb ^ ((row & 7) << 4)));
        }
    }
    int cbase = wave * (N2 / 4);
#pragma unroll
    for (int cg = 0; cg < CGB; ++cg) {
        int c0 = cbase + cg * 16;
        bf16x8 bfr[4];
#pragma unroll
        for (int ks = 0; ks < 4; ++ks)
            bfr[ks] = *(const bf16x8*)(WTn + (size_t)(c0 + lrow) * 128 + ks * 32 + g * 8);
        unsigned short* dstp = (c0 < NOUTN) ? Yn : Zn;
        int cb = ((c0 < NOUTN) ? c0 : c0 - NOUTN) + g * 4;
#pragma unroll
        for (int s = 0; s < 4; ++s) {
            f32x4 acc = {0.f, 0.f, 0.f, 0.f};
#pragma unroll
            for (int ks = 0; ks < 4; ++ks)
                acc = __builtin_amdgcn_mfma_f32_16x16x32_bf16(bfr[ks], af[s][ks], acc, 0, 0, 0);
            int row = nodebase + s * 16 + lrow;
            uint2 w;
            w.x = pk2(acc[0], acc[1]);
            w.y = pk2(acc[2], acc[3]);
            *(uint2*)(dstp + (size_t)row * NOUTN + cb) = w;
        }
    }
}

// ---------------- final aggregation (64-wide, no relu, fp32 out) ----------------

__global__ __launch_bounds__(256) void k_agg_out(const unsigned short* __restrict__ Y,
                                                 const unsigned short* __restrict__ Z,
                                                 const int* __restrict__ row_beg,
                                                 const int* __restrict__ row_end,
                                                 const int* __restrict__ csr,
                                                 const float* __restrict__ b,
                                                 float* __restrict__ outf) {
    int lane = threadIdx.x & 63;
    int n = __builtin_amdgcn_readfirstlane(blockIdx.x * 4 + (threadIdx.x >> 6));
    if (n >= NN) return;
    int beg = __builtin_amdgcn_readfirstlane(row_beg[n]);
    int end = __builtin_amdgcn_readfirstlane(row_end[n]);
    float inv = (end > beg) ? 1.0f / (float)(end - beg) : 0.0f;

    float a0 = 0.f;
    int e = beg;
    for (; e + 8 <= end; e += 8) {
        int s0 = csr[e + 0], s1 = csr[e + 1], s2 = csr[e + 2], s3 = csr[e + 3];
        int s4 = csr[e + 4], s5 = csr[e + 5], s6 = csr[e + 6], s7 = csr[e + 7];
        float f0 = bf2f(Y[(size_t)s0 * 64 + lane]);
        float f1 = bf2f(Y[(size_t)s1 * 64 + lane]);
        float f2 = bf2f(Y[(size_t)s2 * 64 + lane]);
        float f3 = bf2f(Y[(size_t)s3 * 64 + lane]);
        float f4 = bf2f(Y[(size_t)s4 * 64 + lane]);
        float f5 = bf2f(Y[(size_t)s5 * 64 + lane]);
        float f6 = bf2f(Y[(size_t)s6 * 64 + lane]);
        float f7 = bf2f(Y[(size_t)s7 * 64 + lane]);
        a0 += f0 + f1 + f2 + f3 + f4 + f5 + f6 + f7;
    }
    for (; e + 4 <= end; e += 4) {
        int s0 = csr[e + 0], s1 = csr[e + 1], s2 = csr[e + 2], s3 = csr[e + 3];
        float f0 = bf2f(Y[(size_t)s0 * 64 + lane]);
        float f1 = bf2f(Y[(size_t)s1 * 64 + lane]);
        float f2 = bf2f(Y[(size_t)s2 * 64 + lane]);
        float f3 = bf2f(Y[(size_t)s3 * 64 + lane]);
        a0 += f0 + f1 + f2 + f3;
    }
    for (; e < end; ++e) {
        int s = csr[e];
        a0 += bf2f(Y[(size_t)s * 64 + lane]);
    }
    float o = a0 * inv + bf2f(Z[(size_t)n * 64 + lane]) + b[lane];
    outf[(size_t)n * 64 + lane] = o;
}

// ---------------- launch ----------------

extern "C" void kernel_launch(void* const* d_in, const int* in_sizes, int n_in,
                              void* d_out, int out_size, void* d_ws, size_t ws_size,
                              hipStream_t stream) {
    const float* x        = (const float*)d_in[0];
    const int*   ei       = (const int*)d_in[1];
    const float* Wl_stack = (const float*)d_in[2];
    const float* Wr_stack = (const float*)d_in[3];
    const float* b_stack  = (const float*)d_in[4];
    const float* Wl_out   = (const float*)d_in[5];
    const float* Wr_out   = (const float*)d_in[6];
    const float* b_out    = (const float*)d_in[7];
    float* out = (float*)d_out;

    unsigned short* Y0 = (unsigned short*)d_ws;        // [NNP,128]
    unsigned short* Z0 = Y0 + (size_t)NNP * 128;       // [NNP,128]
    unsigned short* Y1 = Z0 + (size_t)NNP * 128;       // [NNP,128]
    unsigned short* Z1 = Y1 + (size_t)NNP * 128;       // [NNP,128]
    unsigned short* WT = Z1 + (size_t)NNP * 128;       // 114688 elems
    unsigned int* ebuf = (unsigned int*)(WT + 114688); // [NBK*CAP]
    int* csr     = (int*)(ebuf + (size_t)NBK * CAP);   // [NBK*CAP] gapped
    int* row_beg = csr + (size_t)NBK * CAP;            // [NN]
    int* row_end = row_beg + NN;                       // [NN]
    int* bcur    = row_end + NN;                       // [NBK]

    const int* src = ei;
    const int* dst = ei + NE;

    // prep: WT conversion + bucket cursor init
    k_prep<<<450, 256, 0, stream>>>(Wl_stack, Wr_stack, Wl_out, Wr_out, WT, bcur);

    // fused: edge scatter (independent) + layer-0 GEMM
    k_fused0<<<NSC + MMG, 256, 0, stream>>>(src, dst, bcur, ebuf, x, WT, Y0, Z0);

    // CSR finalize
    kb_csr<<<NBK, 256, 0, stream>>>(ebuf, bcur, row_beg, row_end, csr);

    // fused agg_l + mm_{l+1}
    k_fagg<128><<<FAGGB, 256, 0, stream>>>(Y0, Z0, row_beg, row_end, csr,
                                           b_stack, WT + 32768, Y1, Z1);
    k_fagg<128><<<FAGGB, 256, 0, stream>>>(Y1, Z1, row_beg, row_end, csr,
                                           b_stack + 128, WT + 65536, Y0, Z0);
    k_fagg<64><<<FAGGB, 256, 0, stream>>>(Y0, Z0, row_beg, row_end, csr,
                                          b_stack + 256, WT + 98304, Y1, Z1);

    // final aggregation -> out (fp32)
    k_agg_out<<<(NN + 3) / 4, 256, 0, stream>>>(Y1, Z1, row_beg, row_end, csr,
                                                b_out, out);
}

// Round 17
// 357.269 us; speedup vs baseline: 1.0939x; 1.0939x over previous
//
#include <hip/hip_runtime.h>

#define NN 100000
#define NNP 100096            // padded row count (multiple of 256)
#define NE 1600000
#define NBK 391               // node buckets of 256 (dst >> 8)
#define CAP 4608              // fixed bucket capacity (mean 4096, +8 sigma)
#define SCCH 4096             // edges per scatter block
#define NSC ((NE + SCCH - 1) / SCCH)   // 391
#define MMG 782               // mm<128> grid (NNP/256 * 2)

typedef __attribute__((ext_vector_type(8))) short bf16x8;
typedef __attribute__((ext_vector_type(4))) float f32x4;

__device__ __forceinline__ float bf2f(unsigned short u) {
    unsigned int v = ((unsigned int)u) << 16;
    return __builtin_bit_cast(float, v);
}
__device__ __forceinline__ unsigned short f2bf(float f) {
    unsigned int u = __builtin_bit_cast(unsigned int, f);
    u += 0x7FFFu + ((u >> 16) & 1u);          // RNE
    return (unsigned short)(u >> 16);
}
__device__ __forceinline__ unsigned int pk2(float lo, float hi) {
    return (unsigned int)f2bf(lo) | ((unsigned int)f2bf(hi) << 16);
}
__device__ __forceinline__ float bflo(unsigned int v) {
    return __builtin_bit_cast(float, v << 16);
}
__device__ __forceinline__ float bfhi(unsigned int v) {
    return __builtin_bit_cast(float, v & 0xFFFF0000u);
}

// bijective XCD-pair map (round-robin dispatch assumed): halves (g, g^1) of a
// row-block land on the same XCD so the second half's A reads hit L2.
// counts over MMG=782 with physical offset `off`: 98 if ((u-off)&7)<6 else 97.
__device__ __forceinline__ int mm_gmap(int bid, int off) {
    int x = (bid + off) & 7;
    int j = bid >> 3;
    int g = j;
#pragma unroll
    for (int u = 0; u < 8; ++u)
        if (u < x) g += ((((u - off) & 7) < 6) ? 98 : 97);
    return g;
}

// ---------------- prep: W -> WT bf16, bcur init ----------------

__global__ __launch_bounds__(256) void k_prep(const float* __restrict__ Wl_stack,
                                              const float* __restrict__ Wr_stack,
                                              const float* __restrict__ Wl_out,
                                              const float* __restrict__ Wr_out,
                                              unsigned short* __restrict__ WT,
                                              int* __restrict__ bcur) {
    int i = blockIdx.x * 256 + threadIdx.x;
    const int L3OFF = 3 * 256 * 128;     // 98304
    const int TOT = L3OFF + 128 * 128;   // 114688
    if (i < TOT) {
        float v;
        if (i < L3OFF) {
            int l = i / (256 * 128);
            int r = i % (256 * 128);
            int c = r / 128;
            int k = r % 128;
            v = (c < 128) ? Wl_stack[(size_t)(l * 128 + k) * 128 + c]
                          : Wr_stack[(size_t)(l * 128 + k) * 128 + (c - 128)];
        } else {
            int r = i - L3OFF;
            int c = r / 128;
            int k = r % 128;
            v = (c < 64) ? Wl_out[(size_t)k * 64 + c]
                         : Wr_out[(size_t)k * 64 + (c - 64)];
        }
        WT[i] = f2bf(v);
    } else if (i - TOT < NBK) {
        bcur[i - TOT] = (i - TOT) * CAP;
    }
}

// ---------------- edge scatter (standalone) ----------------

__global__ __launch_bounds__(256) void k_scatter(const int* __restrict__ src,
                                                 const int* __restrict__ dst,
                                                 int* __restrict__ bcur,
                                                 unsigned int* __restrict__ ebuf) {
    __shared__ int lh[NBK], lbase[NBK];
    int tid = threadIdx.x;
    for (int i = tid; i < NBK; i += 256) lh[i] = 0;
    __syncthreads();
    int base = blockIdx.x * SCCH;
    int lim = min(SCCH, NE - base);
    for (int i = tid; i < lim; i += 256)
        atomicAdd(&lh[dst[base + i] >> 8], 1);
    __syncthreads();
    for (int i = tid; i < NBK; i += 256)
        lbase[i] = lh[i] ? atomicAdd(&bcur[i], lh[i]) : 0;
    __syncthreads();
    for (int i = tid; i < NBK; i += 256) lh[i] = 0;
    __syncthreads();
    for (int i = tid; i < lim; i += 256) {
        int d = dst[base + i];
        int s = src[base + i];
        int b = d >> 8;
        int off = atomicAdd(&lh[b], 1);
        ebuf[(size_t)lbase[b] + off] = ((unsigned)s << 8) | (unsigned)(d & 255);
    }
}

// ---------------- device bodies ----------------

// MFMA dual GEMM body. Block covers 256 rows x 128 cols (one [Wl|Wr] half for
// NOUT=128; whole 128 cols for NOUT=64). WT half (32 KB) staged in LDS with XOR
// swizzle (colb ^= (row&7)<<4). Operand-swapped MFMA -> uint2 row-major stores.
template <int NOUT, bool F32IN>
__device__ __forceinline__ void mm_body(int bid, int xoff, int tid,
                                        const void* __restrict__ Ain,
                                        const unsigned short* __restrict__ WT,
                                        unsigned short* __restrict__ Y,
                                        unsigned short* __restrict__ Z,
                                        unsigned char* lds) {
    constexpr int HALVES = NOUT / 64;           // 2 for 128, 1 for 64
    int wave = tid >> 6, l = tid & 63;
    int lrow = l & 15, g = l >> 4;
    int half, rowblk;
    if (HALVES == 2) {
        int gm = mm_gmap(bid, xoff);
        half = gm & 1;
        rowblk = gm >> 1;
    } else {
        half = 0;
        rowblk = bid;
    }
    int rbase = rowblk * 256 + wave * 64;

    // stage WT half: 32768 B, 256 threads x 8 x 16B
    {
        const unsigned char* wsrc = (const unsigned char*)(WT + (size_t)half * 128 * 128);
#pragma unroll
        for (int j = 0; j < 8; ++j) {
            int lin = (j * 256 + tid) * 16;
            uint4 v = *(const uint4*)(wsrc + lin);
            int row = lin >> 8;
            int colb = lin & 255;
            *(uint4*)(lds + row * 256 + (colb ^ ((row & 7) << 4))) = v;
        }
    }

    // A fragments: 4 strips of 16 rows
    bf16x8 af[4][4];
#pragma unroll
    for (int s = 0; s < 4; ++s) {
        int row = rbase + s * 16 + lrow;
#pragma unroll
        for (int ks = 0; ks < 4; ++ks) {
            if (F32IN) {
                int rc = row < NN ? row : NN - 1;   // x not padded past NN
                const float* ap = (const float*)Ain + (size_t)rc * 128 + ks * 32 + g * 8;
                float4 a = *(const float4*)ap;
                float4 b = *(const float4*)(ap + 4);
                uint4 u;
                u.x = pk2(a.x, a.y); u.y = pk2(a.z, a.w);
                u.z = pk2(b.x, b.y); u.w = pk2(b.z, b.w);
                af[s][ks] = __builtin_bit_cast(bf16x8, u);
            } else {
                af[s][ks] = *(const bf16x8*)((const unsigned short*)Ain
                                             + (size_t)row * 128 + ks * 32 + g * 8);
            }
        }
    }
    __syncthreads();

#pragma unroll
    for (int cg = 0; cg < 8; ++cg) {
        int c0 = cg * 16;
        int rl = c0 + lrow;
        bf16x8 bfr[4];
#pragma unroll
        for (int ks = 0; ks < 4; ++ks) {
            int colb = ks * 64 + g * 16;
            bfr[ks] = *(const bf16x8*)(lds + rl * 256 + (colb ^ ((rl & 7) << 4)));
        }
        int gc0 = half * 128 + c0;
        unsigned short* dstp = (gc0 < NOUT) ? Y : Z;
        int cb = ((gc0 < NOUT) ? gc0 : gc0 - NOUT) + g * 4;
#pragma unroll
        for (int s = 0; s < 4; ++s) {
            f32x4 acc = {0.f, 0.f, 0.f, 0.f};
#pragma unroll
            for (int ks = 0; ks < 4; ++ks)
                acc = __builtin_amdgcn_mfma_f32_16x16x32_bf16(bfr[ks], af[s][ks], acc, 0, 0, 0);
            int row = rbase + s * 16 + lrow;
            uint2 w;
            w.x = pk2(acc[0], acc[1]);
            w.y = pk2(acc[2], acc[3]);
            *(uint2*)(dstp + (size_t)row * NOUT + cb) = w;
        }
    }
}

// per-bucket CSR finalize body
__device__ __forceinline__ void csr_body(int bkt, int tid,
                                         const unsigned int* __restrict__ ebuf,
                                         const int* __restrict__ bcur,
                                         int* __restrict__ row_beg,
                                         int* __restrict__ row_end,
                                         int* __restrict__ csr,
                                         unsigned char* smem) {
    int* sdeg = (int*)smem;
    int* spre = sdeg + 256;
    int nbase = bkt << 8;
    int ebeg = bkt * CAP;
    int eend = bcur[bkt];
    sdeg[tid] = 0;
    __syncthreads();
    for (int e = ebeg + tid; e < eend; e += 256)
        atomicAdd(&sdeg[ebuf[e] & 255], 1);
    __syncthreads();
    spre[tid] = sdeg[tid];
    __syncthreads();
#pragma unroll
    for (int off = 1; off < 256; off <<= 1) {
        int t = (tid >= off) ? spre[tid - off] : 0;
        __syncthreads();
        if (tid >= off) spre[tid] += t;
        __syncthreads();
    }
    int excl = spre[tid] - sdeg[tid];
    if (nbase + tid < NN) {
        row_beg[nbase + tid] = ebeg + excl;
        row_end[nbase + tid] = ebeg + excl + sdeg[tid];
    }
    __syncthreads();
    sdeg[tid] = excl;
    __syncthreads();
    for (int e = ebeg + tid; e < eend; e += 256) {
        unsigned int v = ebuf[e];
        int p = atomicAdd(&sdeg[v & 255], 1);
        csr[ebeg + p] = (int)(v >> 8);
    }
}

// ---------------- fused dispatch: CSR finalize (indep) + layer-0 GEMM ----------------

__global__ __launch_bounds__(256) void k_fused1(const unsigned int* __restrict__ ebuf,
                                                const int* __restrict__ bcur,
                                                int* __restrict__ row_beg,
                                                int* __restrict__ row_end,
                                                int* __restrict__ csr,
                                                const float* __restrict__ x,
                                                const unsigned short* __restrict__ WT,
                                                unsigned short* __restrict__ Y,
                                                unsigned short* __restrict__ Z) {
    __shared__ unsigned char smem[32768];
    int tid = threadIdx.x;
    if (blockIdx.x < NBK) {
        csr_body(blockIdx.x, tid, ebuf, bcur, row_beg, row_end, csr, smem);
    } else {
        // physical bid = NBK + b; NBK % 8 == 7 -> xoff = 7
        mm_body<128, true>(blockIdx.x - NBK, 7, tid, x, WT, Y, Z, smem);
    }
}

// ---------------- standalone GEMM kernels ----------------

template <int NOUT>
__global__ __launch_bounds__(256) void k_mm(const unsigned short* __restrict__ Ain,
                                            const unsigned short* __restrict__ WT,
                                            unsigned short* __restrict__ Y,
                                            unsigned short* __restrict__ Z) {
    __shared__ unsigned char lds[32768];
    mm_body<NOUT, false>(blockIdx.x, 0, threadIdx.x, Ain, WT, Y, Z, lds);
}

// ---------------- aggregation (bf16 gather, scalar edge stream) ----------------

template <int NOUT, bool RELU>
__global__ __launch_bounds__(256) void k_aggb(const unsigned short* __restrict__ Y,
                                              const unsigned short* __restrict__ Z,
                                              const int* __restrict__ row_beg,
                                              const int* __restrict__ row_end,
                                              const int* __restrict__ csr,
                                              const float* __restrict__ b,
                                              unsigned short* __restrict__ outb,
                                              float* __restrict__ outf) {
    int lane = threadIdx.x & 63;
    int n = __builtin_amdgcn_readfirstlane(blockIdx.x * 4 + (threadIdx.x >> 6));
    if (n >= NN) return;
    int beg = __builtin_amdgcn_readfirstlane(row_beg[n]);
    int end = __builtin_amdgcn_readfirstlane(row_end[n]);
    float inv = (end > beg) ? 1.0f / (float)(end - beg) : 0.0f;

    if (NOUT == 128) {
        const int lane2 = lane * 2;
        float a0 = 0.f, a1 = 0.f;
        int e = beg;
        for (; e + 8 <= end; e += 8) {
            int s0 = csr[e + 0], s1 = csr[e + 1], s2 = csr[e + 2], s3 = csr[e + 3];
            int s4 = csr[e + 4], s5 = csr[e + 5], s6 = csr[e + 6], s7 = csr[e + 7];
            unsigned int v0 = *(const unsigned int*)(Y + (size_t)s0 * 128 + lane2);
            unsigned int v1 = *(const unsigned int*)(Y + (size_t)s1 * 128 + lane2);
            unsigned int v2 = *(const unsigned int*)(Y + (size_t)s2 * 128 + lane2);
            unsigned int v3 = *(const unsigned int*)(Y + (size_t)s3 * 128 + lane2);
            unsigned int v4 = *(const unsigned int*)(Y + (size_t)s4 * 128 + lane2);
            unsigned int v5 = *(const unsigned int*)(Y + (size_t)s5 * 128 + lane2);
            unsigned int v6 = *(const unsigned int*)(Y + (size_t)s6 * 128 + lane2);
            unsigned int v7 = *(const unsigned int*)(Y + (size_t)s7 * 128 + lane2);
            a0 += bflo(v0) + bflo(v1) + bflo(v2) + bflo(v3)
                + bflo(v4) + bflo(v5) + bflo(v6) + bflo(v7);
            a1 += bfhi(v0) + bfhi(v1) + bfhi(v2) + bfhi(v3)
                + bfhi(v4) + bfhi(v5) + bfhi(v6) + bfhi(v7);
        }
        for (; e + 4 <= end; e += 4) {
            int s0 = csr[e + 0], s1 = csr[e + 1], s2 = csr[e + 2], s3 = csr[e + 3];
            unsigned int v0 = *(const unsigned int*)(Y + (size_t)s0 * 128 + lane2);
            unsigned int v1 = *(const unsigned int*)(Y + (size_t)s1 * 128 + lane2);
            unsigned int v2 = *(const unsigned int*)(Y + (size_t)s2 * 128 + lane2);
            unsigned int v3 = *(const unsigned int*)(Y + (size_t)s3 * 128 + lane2);
            a0 += bflo(v0) + bflo(v1) + bflo(v2) + bflo(v3);
            a1 += bfhi(v0) + bfhi(v1) + bfhi(v2) + bfhi(v3);
        }
        for (; e < end; ++e) {
            int s = csr[e];
            unsigned int v = *(const unsigned int*)(Y + (size_t)s * 128 + lane2);
            a0 += bflo(v);
            a1 += bfhi(v);
        }
        unsigned int zv = *(const unsigned int*)(Z + (size_t)n * 128 + lane2);
        float2 bb = *(const float2*)(b + lane2);
        float o0 = a0 * inv + bflo(zv) + bb.x;
        float o1 = a1 * inv + bfhi(zv) + bb.y;
        if (RELU) {
            o0 = o0 > 0.f ? o0 : 0.1f * o0;
            o1 = o1 > 0.f ? o1 : 0.1f * o1;
        }
        *(unsigned int*)(outb + (size_t)n * 128 + lane2) = pk2(o0, o1);
    } else {
        float a0 = 0.f;
        int e = beg;
        for (; e + 8 <= end; e += 8) {
            int s0 = csr[e + 0], s1 = csr[e + 1], s2 = csr[e + 2], s3 = csr[e + 3];
            int s4 = csr[e + 4], s5 = csr[e + 5], s6 = csr[e + 6], s7 = csr[e + 7];
            float f0 = bf2f(Y[(size_t)s0 * 64 + lane]);
            float f1 = bf2f(Y[(size_t)s1 * 64 + lane]);
            float f2 = bf2f(Y[(size_t)s2 * 64 + lane]);
            float f3 = bf2f(Y[(size_t)s3 * 64 + lane]);
            float f4 = bf2f(Y[(size_t)s4 * 64 + lane]);
            float f5 = bf2f(Y[(size_t)s5 * 64 + lane]);
            float f6 = bf2f(Y[(size_t)s6 * 64 + lane]);
            float f7 = bf2f(Y[(size_t)s7 * 64 + lane]);
            a0 += f0 + f1 + f2 + f3 + f4 + f5 + f6 + f7;
        }
        for (; e + 4 <= end; e += 4) {
            int s0 = csr[e + 0], s1 = csr[e + 1], s2 = csr[e + 2], s3 = csr[e + 3];
            float f0 = bf2f(Y[(size_t)s0 * 64 + lane]);
            float f1 = bf2f(Y[(size_t)s1 * 64 + lane]);
            float f2 = bf2f(Y[(size_t)s2 * 64 + lane]);
            float f3 = bf2f(Y[(size_t)s3 * 64 + lane]);
            a0 += f0 + f1 + f2 + f3;
        }
        for (; e < end; ++e) {
            int s = csr[e];
            a0 += bf2f(Y[(size_t)s * 64 + lane]);
        }
        float o = a0 * inv + bf2f(Z[(size_t)n * 64 + lane]) + b[lane];
        if (RELU) o = o > 0.f ? o : 0.1f * o;
        outf[(size_t)n * 64 + lane] = o;
    }
}

// ---------------- launch ----------------

extern "C" void kernel_launch(void* const* d_in, const int* in_sizes, int n_in,
                              void* d_out, int out_size, void* d_ws, size_t ws_size,
                              hipStream_t stream) {
    const float* x        = (const float*)d_in[0];
    const int*   ei       = (const int*)d_in[1];
    const float* Wl_stack = (const float*)d_in[2];
    const float* Wr_stack = (const float*)d_in[3];
    const float* b_stack  = (const float*)d_in[4];
    const float* Wl_out   = (const float*)d_in[5];
    const float* Wr_out   = (const float*)d_in[6];
    const float* b_out    = (const float*)d_in[7];
    float* out = (float*)d_out;

    unsigned short* hb = (unsigned short*)d_ws;        // [NNP,128]
    unsigned short* Yb = hb + (size_t)NNP * 128;       // [NNP,128]
    unsigned short* Zb = Yb + (size_t)NNP * 128;       // [NNP,128]
    unsigned short* WT = Zb + (size_t)NNP * 128;       // 114688 elems
    unsigned int* ebuf = (unsigned int*)(WT + 114688); // [NBK*CAP]
    int* csr     = (int*)(ebuf + (size_t)NBK * CAP);   // [NBK*CAP] gapped
    int* row_beg = csr + (size_t)NBK * CAP;            // [NN]
    int* row_end = row_beg + NN;                       // [NN]
    int* bcur    = row_end + NN;                       // [NBK]

    const int* src = ei;
    const int* dst = ei + NE;

    // prep: WT conversion + bucket cursor init
    k_prep<<<450, 256, 0, stream>>>(Wl_stack, Wr_stack, Wl_out, Wr_out, WT, bcur);

    // edge scatter (standalone)
    k_scatter<<<NSC, 256, 0, stream>>>(src, dst, bcur, ebuf);

    // fused: CSR finalize (needs scatter) + layer-0 GEMM (independent)
    k_fused1<<<NBK + MMG, 256, 0, stream>>>(ebuf, bcur, row_beg, row_end, csr,
                                            x, WT, Yb, Zb);

    // layer 0 agg
    k_aggb<128, true><<<(NN + 3) / 4, 256, 0, stream>>>(Yb, Zb, row_beg, row_end, csr,
                                                        b_stack, hb, nullptr);
    // layers 1..2
    for (int l = 1; l < 3; ++l) {
        k_mm<128><<<MMG, 256, 0, stream>>>(hb, WT + l * 32768, Yb, Zb);
        k_aggb<128, true><<<(NN + 3) / 4, 256, 0, stream>>>(Yb, Zb, row_beg, row_end, csr,
                                                            b_stack + l * 128, hb, nullptr);
    }
    // final layer
    k_mm<64><<<NNP / 256, 256, 0, stream>>>(hb, WT + 98304, Yb, Zb);
    k_aggb<64, false><<<(NN + 3) / 4, 256, 0, stream>>>(Yb, Zb, row_beg, row_end, csr,
                                                        b_out, nullptr, out);
}

// Round 18
// 356.837 us; speedup vs baseline: 1.0952x; 1.0012x over previous
//
#include <hip/hip_runtime.h>

#define NN 100000
#define NNP 100096            // padded row count (multiple of 256)
#define NE 1600000
#define NBK 391               // node buckets of 256 (dst >> 8)
#define CAP 4608              // fixed bucket capacity (mean 4096, +8 sigma)
#define SCCH 4096             // edges per scatter block
#define NSC ((NE + SCCH - 1) / SCCH)   // 391
#define MMG 782               // mm<128> grid (NNP/256 * 2)
#define PREPB 224             // prep blocks in k_sp (114688 / 512)

typedef __attribute__((ext_vector_type(8))) short bf16x8;
typedef __attribute__((ext_vector_type(4))) float f32x4;

__device__ __forceinline__ float bf2f(unsigned short u) {
    unsigned int v = ((unsigned int)u) << 16;
    return __builtin_bit_cast(float, v);
}
__device__ __forceinline__ unsigned short f2bf(float f) {
    unsigned int u = __builtin_bit_cast(unsigned int, f);
    u += 0x7FFFu + ((u >> 16) & 1u);          // RNE
    return (unsigned short)(u >> 16);
}
__device__ __forceinline__ unsigned int pk2(float lo, float hi) {
    return (unsigned int)f2bf(lo) | ((unsigned int)f2bf(hi) << 16);
}
__device__ __forceinline__ float bflo(unsigned int v) {
    return __builtin_bit_cast(float, v << 16);
}
__device__ __forceinline__ float bfhi(unsigned int v) {
    return __builtin_bit_cast(float, v & 0xFFFF0000u);
}

// bijective XCD-pair map (round-robin dispatch assumed): halves (g, g^1) of a
// row-block land on the same XCD so the second half's A reads hit L2.
__device__ __forceinline__ int mm_gmap(int bid, int off) {
    int x = (bid + off) & 7;
    int j = bid >> 3;
    int g = j;
#pragma unroll
    for (int u = 0; u < 8; ++u)
        if (u < x) g += ((((u - off) & 7) < 6) ? 98 : 97);
    return g;
}

// ---------------- fused: edge scatter (512 thr) + W->WT prep ----------------
// bcur is RELATIVE (memset to 0 before); absolute base = bkt*CAP.

__global__ __launch_bounds__(512) void k_sp(const int* __restrict__ src,
                                            const int* __restrict__ dst,
                                            int* __restrict__ bcur,
                                            unsigned int* __restrict__ ebuf,
                                            const float* __restrict__ Wl_stack,
                                            const float* __restrict__ Wr_stack,
                                            const float* __restrict__ Wl_out,
                                            const float* __restrict__ Wr_out,
                                            unsigned short* __restrict__ WT) {
    int tid = threadIdx.x;
    if (blockIdx.x >= NSC) {
        // prep body: WT conversion
        int i = (blockIdx.x - NSC) * 512 + tid;
        const int L3OFF = 3 * 256 * 128;     // 98304
        const int TOT = L3OFF + 128 * 128;   // 114688
        if (i < TOT) {
            float v;
            if (i < L3OFF) {
                int l = i / (256 * 128);
                int r = i % (256 * 128);
                int c = r / 128;
                int k = r % 128;
                v = (c < 128) ? Wl_stack[(size_t)(l * 128 + k) * 128 + c]
                              : Wr_stack[(size_t)(l * 128 + k) * 128 + (c - 128)];
            } else {
                int r = i - L3OFF;
                int c = r / 128;
                int k = r % 128;
                v = (c < 64) ? Wl_out[(size_t)k * 64 + c]
                             : Wr_out[(size_t)k * 64 + (c - 64)];
            }
            WT[i] = f2bf(v);
        }
        return;
    }
    // scatter body
    __shared__ int lh[NBK], lbase[NBK];
    for (int i = tid; i < NBK; i += 512) lh[i] = 0;
    __syncthreads();
    int base = blockIdx.x * SCCH;
    int lim = min(SCCH, NE - base);
    for (int i = tid; i < lim; i += 512)
        atomicAdd(&lh[dst[base + i] >> 8], 1);
    __syncthreads();
    for (int i = tid; i < NBK; i += 512)
        lbase[i] = lh[i] ? (i * CAP + atomicAdd(&bcur[i], lh[i])) : 0;
    __syncthreads();
    for (int i = tid; i < NBK; i += 512) lh[i] = 0;
    __syncthreads();
    for (int i = tid; i < lim; i += 512) {
        int d = dst[base + i];
        int s = src[base + i];
        int b = d >> 8;
        int off = atomicAdd(&lh[b], 1);
        ebuf[(size_t)lbase[b] + off] = ((unsigned)s << 8) | (unsigned)(d & 255);
    }
}

// ---------------- device bodies ----------------

// MFMA dual GEMM body. Block covers (S*64) rows x 128 cols (one [Wl|Wr] half
// for NOUT=128; whole 128 cols for NOUT=64). WT half (32 KB) staged in LDS
// with XOR swizzle (colb ^= (row&7)<<4). Operand-swapped MFMA; uint2 stores.
template <int NOUT, bool F32IN, int S>
__device__ __forceinline__ void mm_body(int bid, int xoff, int tid,
                                        const void* __restrict__ Ain,
                                        const unsigned short* __restrict__ WT,
                                        unsigned short* __restrict__ Y,
                                        unsigned short* __restrict__ Z,
                                        unsigned char* lds) {
    constexpr int HALVES = NOUT / 64;           // 2 for 128, 1 for 64
    int wave = tid >> 6, l = tid & 63;
    int lrow = l & 15, g = l >> 4;
    int half, rowblk;
    if (HALVES == 2) {
        int gm = mm_gmap(bid, xoff);
        half = gm & 1;
        rowblk = gm >> 1;
    } else {
        half = 0;
        rowblk = bid;
    }
    int rbase = rowblk * (S * 64) + wave * (S * 16);

    // stage WT half: 32768 B
    {
        const unsigned char* wsrc = (const unsigned char*)(WT + (size_t)half * 128 * 128);
#pragma unroll
        for (int j = 0; j < 8; ++j) {
            int lin = (j * 256 + tid) * 16;
            uint4 v = *(const uint4*)(wsrc + lin);
            int row = lin >> 8;
            int colb = lin & 255;
            *(uint4*)(lds + row * 256 + (colb ^ ((row & 7) << 4))) = v;
        }
    }

    // A fragments: S strips of 16 rows
    bf16x8 af[S][4];
#pragma unroll
    for (int s = 0; s < S; ++s) {
        int row = rbase + s * 16 + lrow;
#pragma unroll
        for (int ks = 0; ks < 4; ++ks) {
            if (F32IN) {
                int rc = row < NN ? row : NN - 1;   // x not padded past NN
                const float* ap = (const float*)Ain + (size_t)rc * 128 + ks * 32 + g * 8;
                float4 a = *(const float4*)ap;
                float4 b = *(const float4*)(ap + 4);
                uint4 u;
                u.x = pk2(a.x, a.y); u.y = pk2(a.z, a.w);
                u.z = pk2(b.x, b.y); u.w = pk2(b.z, b.w);
                af[s][ks] = __builtin_bit_cast(bf16x8, u);
            } else {
                af[s][ks] = *(const bf16x8*)((const unsigned short*)Ain
                                             + (size_t)row * 128 + ks * 32 + g * 8);
            }
        }
    }
    __syncthreads();

#pragma unroll
    for (int cg = 0; cg < 8; ++cg) {
        int c0 = cg * 16;
        int rl = c0 + lrow;
        bf16x8 bfr[4];
#pragma unroll
        for (int ks = 0; ks < 4; ++ks) {
            int colb = ks * 64 + g * 16;
            bfr[ks] = *(const bf16x8*)(lds + rl * 256 + (colb ^ ((rl & 7) << 4)));
        }
        int gc0 = half * 128 + c0;
        unsigned short* dstp = (gc0 < NOUT) ? Y : Z;
        int cb = ((gc0 < NOUT) ? gc0 : gc0 - NOUT) + g * 4;
#pragma unroll
        for (int s = 0; s < S; ++s) {
            f32x4 acc = {0.f, 0.f, 0.f, 0.f};
#pragma unroll
            for (int ks = 0; ks < 4; ++ks)
                acc = __builtin_amdgcn_mfma_f32_16x16x32_bf16(bfr[ks], af[s][ks], acc, 0, 0, 0);
            int row = rbase + s * 16 + lrow;
            uint2 w;
            w.x = pk2(acc[0], acc[1]);
            w.y = pk2(acc[2], acc[3]);
            *(uint2*)(dstp + (size_t)row * NOUT + cb) = w;
        }
    }
}

// per-bucket CSR finalize body (bcur is relative)
__device__ __forceinline__ void csr_body(int bkt, int tid,
                                         const unsigned int* __restrict__ ebuf,
                                         const int* __restrict__ bcur,
                                         int* __restrict__ row_beg,
                                         int* __restrict__ row_end,
                                         int* __restrict__ csr,
                                         unsigned char* smem) {
    int* sdeg = (int*)smem;
    int* spre = sdeg + 256;
    int nbase = bkt << 8;
    int ebeg = bkt * CAP;
    int eend = ebeg + bcur[bkt];
    sdeg[tid] = 0;
    __syncthreads();
    for (int e = ebeg + tid; e < eend; e += 256)
        atomicAdd(&sdeg[ebuf[e] & 255], 1);
    __syncthreads();
    spre[tid] = sdeg[tid];
    __syncthreads();
#pragma unroll
    for (int off = 1; off < 256; off <<= 1) {
        int t = (tid >= off) ? spre[tid - off] : 0;
        __syncthreads();
        if (tid >= off) spre[tid] += t;
        __syncthreads();
    }
    int excl = spre[tid] - sdeg[tid];
    if (nbase + tid < NN) {
        row_beg[nbase + tid] = ebeg + excl;
        row_end[nbase + tid] = ebeg + excl + sdeg[tid];
    }
    __syncthreads();
    sdeg[tid] = excl;
    __syncthreads();
    for (int e = ebeg + tid; e < eend; e += 256) {
        unsigned int v = ebuf[e];
        int p = atomicAdd(&sdeg[v & 255], 1);
        csr[ebeg + p] = (int)(v >> 8);
    }
}

// ---------------- fused dispatch: CSR finalize (indep) + layer-0 GEMM ----------------

__global__ __launch_bounds__(256) void k_fused1(const unsigned int* __restrict__ ebuf,
                                                const int* __restrict__ bcur,
                                                int* __restrict__ row_beg,
                                                int* __restrict__ row_end,
                                                int* __restrict__ csr,
                                                const float* __restrict__ x,
                                                const unsigned short* __restrict__ WT,
                                                unsigned short* __restrict__ Y,
                                                unsigned short* __restrict__ Z) {
    __shared__ unsigned char smem[32768];
    int tid = threadIdx.x;
    if (blockIdx.x < NBK) {
        csr_body(blockIdx.x, tid, ebuf, bcur, row_beg, row_end, csr, smem);
    } else {
        // physical bid = NBK + b; NBK % 8 == 7 -> xoff = 7
        mm_body<128, true, 4>(blockIdx.x - NBK, 7, tid, x, WT, Y, Z, smem);
    }
}

// ---------------- standalone GEMM kernels ----------------

template <int NOUT, int S>
__global__ __launch_bounds__(256) void k_mm(const unsigned short* __restrict__ Ain,
                                            const unsigned short* __restrict__ WT,
                                            unsigned short* __restrict__ Y,
                                            unsigned short* __restrict__ Z) {
    __shared__ unsigned char lds[32768];
    mm_body<NOUT, false, S>(blockIdx.x, 0, threadIdx.x, Ain, WT, Y, Z, lds);
}

// ---------------- aggregation (bf16 gather, scalar edge stream) ----------------

template <int NOUT, bool RELU>
__global__ __launch_bounds__(256) void k_aggb(const unsigned short* __restrict__ Y,
                                              const unsigned short* __restrict__ Z,
                                              const int* __restrict__ row_beg,
                                              const int* __restrict__ row_end,
                                              const int* __restrict__ csr,
                                              const float* __restrict__ b,
                                              unsigned short* __restrict__ outb,
                                              float* __restrict__ outf) {
    int lane = threadIdx.x & 63;
    int n = __builtin_amdgcn_readfirstlane(blockIdx.x * 4 + (threadIdx.x >> 6));
    if (n >= NN) return;
    int beg = __builtin_amdgcn_readfirstlane(row_beg[n]);
    int end = __builtin_amdgcn_readfirstlane(row_end[n]);
    float inv = (end > beg) ? 1.0f / (float)(end - beg) : 0.0f;

    if (NOUT == 128) {
        const int lane2 = lane * 2;
        float a0 = 0.f, a1 = 0.f;
        int e = beg;
        for (; e + 8 <= end; e += 8) {
            int s0 = csr[e + 0], s1 = csr[e + 1], s2 = csr[e + 2], s3 = csr[e + 3];
            int s4 = csr[e + 4], s5 = csr[e + 5], s6 = csr[e + 6], s7 = csr[e + 7];
            unsigned int v0 = *(const unsigned int*)(Y + (size_t)s0 * 128 + lane2);
            unsigned int v1 = *(const unsigned int*)(Y + (size_t)s1 * 128 + lane2);
            unsigned int v2 = *(const unsigned int*)(Y + (size_t)s2 * 128 + lane2);
            unsigned int v3 = *(const unsigned int*)(Y + (size_t)s3 * 128 + lane2);
            unsigned int v4 = *(const unsigned int*)(Y + (size_t)s4 * 128 + lane2);
            unsigned int v5 = *(const unsigned int*)(Y + (size_t)s5 * 128 + lane2);
            unsigned int v6 = *(const unsigned int*)(Y + (size_t)s6 * 128 + lane2);
            unsigned int v7 = *(const unsigned int*)(Y + (size_t)s7 * 128 + lane2);
            a0 += bflo(v0) + bflo(v1) + bflo(v2) + bflo(v3)
                + bflo(v4) + bflo(v5) + bflo(v6) + bflo(v7);
            a1 += bfhi(v0) + bfhi(v1) + bfhi(v2) + bfhi(v3)
                + bfhi(v4) + bfhi(v5) + bfhi(v6) + bfhi(v7);
        }
        for (; e + 4 <= end; e += 4) {
            int s0 = csr[e + 0], s1 = csr[e + 1], s2 = csr[e + 2], s3 = csr[e + 3];
            unsigned int v0 = *(const unsigned int*)(Y + (size_t)s0 * 128 + lane2);
            unsigned int v1 = *(const unsigned int*)(Y + (size_t)s1 * 128 + lane2);
            unsigned int v2 = *(const unsigned int*)(Y + (size_t)s2 * 128 + lane2);
            unsigned int v3 = *(const unsigned int*)(Y + (size_t)s3 * 128 + lane2);
            a0 += bflo(v0) + bflo(v1) + bflo(v2) + bflo(v3);
            a1 += bfhi(v0) + bfhi(v1) + bfhi(v2) + bfhi(v3);
        }
        for (; e < end; ++e) {
            int s = csr[e];
            unsigned int v = *(const unsigned int*)(Y + (size_t)s * 128 + lane2);
            a0 += bflo(v);
            a1 += bfhi(v);
        }
        unsigned int zv = *(const unsigned int*)(Z + (size_t)n * 128 + lane2);
        float2 bb = *(const float2*)(b + lane2);
        float o0 = a0 * inv + bflo(zv) + bb.x;
        float o1 = a1 * inv + bfhi(zv) + bb.y;
        if (RELU) {
            o0 = o0 > 0.f ? o0 : 0.1f * o0;
            o1 = o1 > 0.f ? o1 : 0.1f * o1;
        }
        *(unsigned int*)(outb + (size_t)n * 128 + lane2) = pk2(o0, o1);
    } else {
        float a0 = 0.f;
        int e = beg;
        for (; e + 8 <= end; e += 8) {
            int s0 = csr[e + 0], s1 = csr[e + 1], s2 = csr[e + 2], s3 = csr[e + 3];
            int s4 = csr[e + 4], s5 = csr[e + 5], s6 = csr[e + 6], s7 = csr[e + 7];
            float f0 = bf2f(Y[(size_t)s0 * 64 + lane]);
            float f1 = bf2f(Y[(size_t)s1 * 64 + lane]);
            float f2 = bf2f(Y[(size_t)s2 * 64 + lane]);
            float f3 = bf2f(Y[(size_t)s3 * 64 + lane]);
            float f4 = bf2f(Y[(size_t)s4 * 64 + lane]);
            float f5 = bf2f(Y[(size_t)s5 * 64 + lane]);
            float f6 = bf2f(Y[(size_t)s6 * 64 + lane]);
            float f7 = bf2f(Y[(size_t)s7 * 64 + lane]);
            a0 += f0 + f1 + f2 + f3 + f4 + f5 + f6 + f7;
        }
        for (; e + 4 <= end; e += 4) {
            int s0 = csr[e + 0], s1 = csr[e + 1], s2 = csr[e + 2], s3 = csr[e + 3];
            float f0 = bf2f(Y[(size_t)s0 * 64 + lane]);
            float f1 = bf2f(Y[(size_t)s1 * 64 + lane]);
            float f2 = bf2f(Y[(size_t)s2 * 64 + lane]);
            float f3 = bf2f(Y[(size_t)s3 * 64 + lane]);
            a0 += f0 + f1 + f2 + f3;
        }
        for (; e < end; ++e) {
            int s = csr[e];
            a0 += bf2f(Y[(size_t)s * 64 + lane]);
        }
        float o = a0 * inv + bf2f(Z[(size_t)n * 64 + lane]) + b[lane];
        if (RELU) o = o > 0.f ? o : 0.1f * o;
        outf[(size_t)n * 64 + lane] = o;
    }
}

// ---------------- launch ----------------

extern "C" void kernel_launch(void* const* d_in, const int* in_sizes, int n_in,
                              void* d_out, int out_size, void* d_ws, size_t ws_size,
                              hipStream_t stream) {
    const float* x        = (const float*)d_in[0];
    const int*   ei       = (const int*)d_in[1];
    const float* Wl_stack = (const float*)d_in[2];
    const float* Wr_stack = (const float*)d_in[3];
    const float* b_stack  = (const float*)d_in[4];
    const float* Wl_out   = (const float*)d_in[5];
    const float* Wr_out   = (const float*)d_in[6];
    const float* b_out    = (const float*)d_in[7];
    float* out = (float*)d_out;

    unsigned short* hb = (unsigned short*)d_ws;        // [NNP,128]
    unsigned short* Yb = hb + (size_t)NNP * 128;       // [NNP,128]
    unsigned short* Zb = Yb + (size_t)NNP * 128;       // [NNP,128]
    unsigned short* WT = Zb + (size_t)NNP * 128;       // 114688 elems
    unsigned int* ebuf = (unsigned int*)(WT + 114688); // [NBK*CAP]
    int* csr     = (int*)(ebuf + (size_t)NBK * CAP);   // [NBK*CAP] gapped
    int* row_beg = csr + (size_t)NBK * CAP;            // [NN]
    int* row_end = row_beg + NN;                       // [NN]
    int* bcur    = row_end + NN;                       // [NBK]

    const int* src = ei;
    const int* dst = ei + NE;

    // bucket cursors (relative) -> 0
    (void)hipMemsetAsync(bcur, 0, NBK * sizeof(int), stream);

    // fused: edge scatter (512 thr) + WT prep
    k_sp<<<NSC + PREPB, 512, 0, stream>>>(src, dst, bcur, ebuf,
                                          Wl_stack, Wr_stack, Wl_out, Wr_out, WT);

    // fused: CSR finalize (needs scatter) + layer-0 GEMM (needs WT)
    k_fused1<<<NBK + MMG, 256, 0, stream>>>(ebuf, bcur, row_beg, row_end, csr,
                                            x, WT, Yb, Zb);

    // layer 0 agg
    k_aggb<128, true><<<(NN + 3) / 4, 256, 0, stream>>>(Yb, Zb, row_beg, row_end, csr,
                                                        b_stack, hb, nullptr);
    // layers 1..2
    for (int l = 1; l < 3; ++l) {
        k_mm<128, 4><<<MMG, 256, 0, stream>>>(hb, WT + l * 32768, Yb, Zb);
        k_aggb<128, true><<<(NN + 3) / 4, 256, 0, stream>>>(Yb, Zb, row_beg, row_end, csr,
                                                            b_stack + l * 128, hb, nullptr);
    }
    // final layer (128-row blocks for occupancy)
    k_mm<64, 2><<<NNP / 128, 256, 0, stream>>>(hb, WT + 98304, Yb, Zb);
    k_aggb<64, false><<<(NN + 3) / 4, 256, 0, stream>>>(Yb, Zb, row_beg, row_end, csr,
                                                        b_out, nullptr, out);
}